// Round 7
// baseline (489.008 us; speedup 1.0000x reference)
//
#include <hip/hip_runtime.h>
#include <math.h>

// ---------------------------------------------------------------------------
// SwinV2 stage: B=32, H=W=56, C=128, NH=4, hd=32, WS=7, N=49, DEPTH=2, shift=3
// Round 7: attn restructured -> per-q-tile P staging (LDS 55->27.6 KB/block,
// 2->5 blocks/CU), V loads issued before normalize VALU chain, setprio on
// MFMA clusters. GEMMs unchanged from R6.
// ---------------------------------------------------------------------------

namespace {
constexpr int kTok = 32 * 56 * 56;   // 100352 tokens
}

typedef __attribute__((ext_vector_type(8))) short bf16x8;
typedef __attribute__((ext_vector_type(4))) float f32x4;

union FragU {
    int4 i4;
    bf16x8 b8;
    unsigned short u[8];
};

__device__ __forceinline__ short f2bf(float f) {
    unsigned u = __float_as_uint(f);
    return (short)((u + 0x7FFFu + ((u >> 16) & 1u)) >> 16);
}
__device__ __forceinline__ float bf2f(unsigned short u) {
    return __uint_as_float(((unsigned)u) << 16);
}
__device__ __forceinline__ float gelu_f(float x) {
    return 0.5f * x * (1.0f + erff(x * 0.70710678118654752f));
}

// --------------------------- CPB MLP (tiny) --------------------------------
__global__ __launch_bounds__(256) void k_cpb(
    const float* __restrict__ w1, const float* __restrict__ b1,
    const float* __restrict__ w2, float* __restrict__ out169) {
    int t = blockIdx.x;  // 0..168
    int ia = t / 13, ib = t % 13;
    float r0 = (float)(ia - 6) * (8.0f / 6.0f);
    float s0 = (r0 > 0.f) ? 1.f : (r0 < 0.f ? -1.f : 0.f);
    float t0 = s0 * log2f(fabsf(r0) + 1.0f) * (1.0f / 3.0f);
    float r1 = (float)(ib - 6) * (8.0f / 6.0f);
    float s1 = (r1 > 0.f) ? 1.f : (r1 < 0.f ? -1.f : 0.f);
    float t1 = s1 * log2f(fabsf(r1) + 1.0f) * (1.0f / 3.0f);

    int tid = threadIdx.x;
    float p0 = 0, p1 = 0, p2 = 0, p3 = 0;
    for (int c = tid; c < 512; c += 256) {
        float hv = fmaxf(t0 * w1[c] + t1 * w1[512 + c] + b1[c], 0.0f);
        p0 += hv * w2[c * 4 + 0];
        p1 += hv * w2[c * 4 + 1];
        p2 += hv * w2[c * 4 + 2];
        p3 += hv * w2[c * 4 + 3];
    }
    __shared__ float red[256][4];
    red[tid][0] = p0; red[tid][1] = p1; red[tid][2] = p2; red[tid][3] = p3;
    __syncthreads();
    for (int s = 128; s > 0; s >>= 1) {
        if (tid < s) {
            red[tid][0] += red[tid + s][0];
            red[tid][1] += red[tid + s][1];
            red[tid][2] += red[tid + s][2];
            red[tid][3] += red[tid + s][3];
        }
        __syncthreads();
    }
    if (tid < 4) out169[t * 4 + tid] = red[0][tid];
}

// rpb64[h][qrow64][krow64]; krow>=49 -> -30000 (k-pad baked in)
__global__ void k_rpb(const float* __restrict__ out169, float* __restrict__ rpb64) {
    int e = blockIdx.x * 256 + threadIdx.x;
    if (e >= 4 * 64 * 64) return;
    int h = e >> 12, r = e & 4095;
    int i = r >> 6, j = r & 63;
    float val;
    if (j >= 49) {
        val = -30000.0f;
    } else if (i >= 49) {
        val = 0.0f;
    } else {
        int dp = i / 7 - j / 7 + 6;
        int dq = i % 7 - j % 7 + 6;
        float v = out169[(dp * 13 + dq) * 4 + h];
        val = 16.0f / (1.0f + expf(-v));
    }
    rpb64[e] = val;
}

// ------------------- weight fp32 -> bf16 tiled image -----------------------
// Logical slot (nt*Kb + kb)*64 + nn holds W[kb*8+e][nt*64+nn], e=0..7.
// Stored at physical nn' = (nn & ~3) | ((nn ^ kb) & 3).
__global__ __launch_bounds__(256) void k_cvtw(
    const float* __restrict__ W, short* __restrict__ Wb, int Kb, int N) {
    int slt = blockIdx.x * 256 + threadIdx.x;
    if (slt >= Kb * N) return;
    int nn = slt & 63;
    int tmp = slt >> 6;
    int kb = tmp % Kb;
    int nt = tmp / Kb;
    int n = nt * 64 + nn;
    int k0 = kb * 8;
    union { int4 i4; short s8[8]; } u;
#pragma unroll
    for (int e = 0; e < 8; ++e) u.s8[e] = f2bf(W[(size_t)(k0 + e) * N + n]);
    int nns = (nn & ~3) | ((nn ^ kb) & 3);
    *(int4*)(Wb + (((size_t)tmp) * 64 + nns) * 8) = u.i4;
}

// ------------------- activation fp32 -> bf16 rows --------------------------
__global__ __launch_bounds__(256) void k_cvtx(
    const float* __restrict__ x, short* __restrict__ xb) {
    size_t e = ((size_t)blockIdx.x * 256 + threadIdx.x) * 8;
    const float* src = x + e;
    float4 f0 = *(const float4*)src;
    float4 f1 = *(const float4*)(src + 4);
    union { int4 i4; short s8[8]; } u;
    u.s8[0] = f2bf(f0.x); u.s8[1] = f2bf(f0.y);
    u.s8[2] = f2bf(f0.z); u.s8[3] = f2bf(f0.w);
    u.s8[4] = f2bf(f1.x); u.s8[5] = f2bf(f1.y);
    u.s8[6] = f2bf(f1.z); u.s8[7] = f2bf(f1.w);
    *(int4*)(xb + e) = u.i4;
}

// --------------------------- MFMA GEMM (bf16 A) ----------------------------
template <int K, int EPI, int NT>
__global__ __launch_bounds__(256) void k_gemm(
    const short* __restrict__ Ain, const short* __restrict__ Wb,
    const float* __restrict__ bias0, const float* __restrict__ bias1,
    void* __restrict__ Out, int ostride, int shift) {
    constexpr int Kb = K / 8;
    constexpr int NC = K / 128;
    __shared__ int4 As4[2048];  // [16 kb][128 m], XOR-swizzled (8-wide)
    __shared__ int4 Ws4[1024];  // [16 kb][64 nn], XOR-swizzled (4-wide, in image)
    int tid = threadIdx.x;
    int nwg = gridDim.x;
    int chunk = nwg >> 3;
    int lid = (blockIdx.x & 7) * chunk + (blockIdx.x >> 3);
    int mt = lid / NT, nt = lid - mt * NT;
    int mb = mt * 128;
    int w = tid >> 6, l = tid & 63, lr = l & 15, lg = l >> 4;
    const f32x4 fz = {0.f, 0.f, 0.f, 0.f};
    f32x4 acc[2][4];
#pragma unroll
    for (int mi = 0; mi < 2; ++mi)
#pragma unroll
        for (int ni = 0; ni < 4; ++ni) acc[mi][ni] = fz;

    for (int c = 0; c < NC; ++c) {
        if (c) __syncthreads();
#pragma unroll
        for (int it = 0; it < 8; ++it) {
            int s = it * 256 + tid;
            int m = s >> 4, kb = s & 15;
            int gm = mb + m;
            if (EPI == 1 && shift) {
                int b = gm / 3136, r = gm % 3136;
                int hh = r / 56 + shift; if (hh >= 56) hh -= 56;
                int ww = r % 56 + shift; if (ww >= 56) ww -= 56;
                gm = b * 3136 + hh * 56 + ww;
            }
            int slot = kb * 128 + ((m & ~7) | ((m ^ kb) & 7));
            As4[slot] = *(const int4*)(Ain + (size_t)gm * K + c * 128 + kb * 8);
        }
        {
            const int4* wsrc = (const int4*)(Wb + ((size_t)nt * Kb + c * 16) * 64 * 8);
#pragma unroll
            for (int it = 0; it < 4; ++it) Ws4[it * 256 + tid] = wsrc[it * 256 + tid];
        }
        __syncthreads();
#pragma unroll
        for (int kk = 0; kk < 4; ++kk) {
            int kbl = kk * 4 + lg;
            int m0 = w * 32 + lr;
            bf16x8 a0 = *(const bf16x8*)&As4[kbl * 128 + ((m0 & ~7) | ((m0 ^ kbl) & 7))];
            int m1 = m0 + 16;
            bf16x8 a1 = *(const bf16x8*)&As4[kbl * 128 + ((m1 & ~7) | ((m1 ^ kbl) & 7))];
#pragma unroll
            for (int ni = 0; ni < 4; ++ni) {
                int nn = lr + 16 * ni;
                bf16x8 bfr = *(const bf16x8*)&Ws4[kbl * 64 + ((nn & ~3) | ((nn ^ kbl) & 3))];
                acc[0][ni] = __builtin_amdgcn_mfma_f32_16x16x32_bf16(a0, bfr, acc[0][ni], 0, 0, 0);
                acc[1][ni] = __builtin_amdgcn_mfma_f32_16x16x32_bf16(a1, bfr, acc[1][ni], 0, 0, 0);
            }
        }
    }
#pragma unroll
    for (int ni = 0; ni < 4; ++ni) {
        int col = nt * 64 + ni * 16 + lr;
        float bv = 0.f;
        if (EPI == 1) bv = (col < 128) ? bias0[col] : ((col < 256) ? 0.f : bias1[col - 256]);
        if (EPI == 2) bv = bias0[col];
#pragma unroll
        for (int mi = 0; mi < 2; ++mi) {
#pragma unroll
            for (int r = 0; r < 4; ++r) {
                int row = mb + w * 32 + mi * 16 + lg * 4 + r;
                float v = acc[mi][ni][r] + bv;
                if (EPI == 0) {
                    ((float*)Out)[(size_t)row * ostride + col] = v;
                } else if (EPI == 1) {
                    ((short*)Out)[(size_t)row * 384 + col] = f2bf(v);
                } else {
                    ((short*)Out)[(size_t)row * 512 + col] = f2bf(gelu_f(v));
                }
            }
        }
    }
}

// ------------- MFMA GEMM + bias + LN + residual (+roll-back) ---------------
template <int K>
__global__ __launch_bounds__(256) void k_gemm_ln(
    const short* __restrict__ Ain, const short* __restrict__ Wb,
    const float* __restrict__ bias, const float* __restrict__ g,
    const float* __restrict__ bt, const float* __restrict__ resid,
    float* __restrict__ xout, short* __restrict__ xoutb, int shift) {
    constexpr int Kb = K / 8;
    constexpr int NC = K / 128;
    __shared__ int4 As4[1024];  // [16 kb][64 m]
    __shared__ int4 Ws4[2048];  // [2 ntw][16 kb][64 nn]
    int tid = threadIdx.x;
    int mb = blockIdx.x * 64;
    int w = tid >> 6, l = tid & 63, lr = l & 15, lg = l >> 4;
    const f32x4 fz = {0.f, 0.f, 0.f, 0.f};
    f32x4 acc[8];
#pragma unroll
    for (int ni = 0; ni < 8; ++ni) acc[ni] = fz;

    for (int c = 0; c < NC; ++c) {
        if (c) __syncthreads();
#pragma unroll
        for (int it = 0; it < 4; ++it) {
            int s = it * 256 + tid;
            int m = s >> 4, kb = s & 15;
            int slot = kb * 64 + ((m & ~7) | ((m ^ kb) & 7));
            As4[slot] = *(const int4*)(Ain + (size_t)(mb + m) * K + c * 128 + kb * 8);
        }
        {
            const int4* w0 = (const int4*)(Wb + ((size_t)(c * 16)) * 64 * 8);
            const int4* w1 = (const int4*)(Wb + ((size_t)(Kb + c * 16)) * 64 * 8);
#pragma unroll
            for (int it = 0; it < 4; ++it) {
                Ws4[it * 256 + tid] = w0[it * 256 + tid];
                Ws4[1024 + it * 256 + tid] = w1[it * 256 + tid];
            }
        }
        __syncthreads();
#pragma unroll
        for (int kk = 0; kk < 4; ++kk) {
            int kbl = kk * 4 + lg;
            int m0 = w * 16 + lr;
            bf16x8 a0 = *(const bf16x8*)&As4[kbl * 64 + ((m0 & ~7) | ((m0 ^ kbl) & 7))];
#pragma unroll
            for (int ni = 0; ni < 8; ++ni) {
                int nn = lr + 16 * (ni & 3);
                bf16x8 bfr = *(const bf16x8*)&Ws4[(ni >> 2) * 1024 + kbl * 64 +
                                                  ((nn & ~3) | ((nn ^ kbl) & 3))];
                acc[ni] = __builtin_amdgcn_mfma_f32_16x16x32_bf16(a0, bfr, acc[ni], 0, 0, 0);
            }
        }
    }
    float bv[8], gv[8], btv[8];
#pragma unroll
    for (int ni = 0; ni < 8; ++ni) {
        int col = ni * 16 + lr;
        bv[ni] = bias[col]; gv[ni] = g[col]; btv[ni] = bt[col];
    }
#pragma unroll
    for (int r = 0; r < 4; ++r) {
        int row = mb + w * 16 + lg * 4 + r;
        float v[8];
        float s1 = 0.f, s2 = 0.f;
#pragma unroll
        for (int ni = 0; ni < 8; ++ni) {
            v[ni] = acc[ni][r] + bv[ni];
            s1 += v[ni];
            s2 = fmaf(v[ni], v[ni], s2);
        }
#pragma unroll
        for (int off = 8; off >= 1; off >>= 1) {
            s1 += __shfl_xor(s1, off);
            s2 += __shfl_xor(s2, off);
        }
        float mean = s1 * (1.0f / 128.0f);
        float var = s2 * (1.0f / 128.0f) - mean * mean;
        float rstd = rsqrtf(var + 1e-5f);
        int mo = row;
        if (shift) {
            int b = row / 3136, rr = row % 3136;
            int hh = rr / 56 + shift; if (hh >= 56) hh -= 56;
            int ww = rr % 56 + shift; if (ww >= 56) ww -= 56;
            mo = b * 3136 + hh * 56 + ww;
        }
        size_t base = (size_t)mo * 128;
#pragma unroll
        for (int ni = 0; ni < 8; ++ni) {
            int col = ni * 16 + lr;
            float o = resid[base + col] + (v[ni] - mean) * rstd * gv[ni] + btv[ni];
            xout[base + col] = o;
            xoutb[base + col] = f2bf(o);
        }
    }
}

// --------------------------- MFMA windowed attention -----------------------
// grid 2048 (one block per window), 4 waves = 4 heads, all wave-private LDS
// (no barriers). Per wave: Pt[16][72] (one q-tile) + Vt[32][72].
__global__ __launch_bounds__(256) void k_attn(
    const short* __restrict__ qkv, const float* __restrict__ rpb64,
    const float* __restrict__ ls, short* __restrict__ aout, int shift) {
    __shared__ short lds[4 * 3456];
    int wid = blockIdx.x;
    int b = wid >> 6, wrem = wid & 63;
    int wh = wrem >> 3, ww_ = wrem & 7;
    int h = threadIdx.x >> 6;
    int l = threadIdx.x & 63, lr = l & 15, lg = l >> 4;
    short* Pt = lds + h * 3456;   // 1152 shorts: [16 qrow][72]
    short* Vt = Pt + 1152;        // 2304 shorts: [32 d][72]
    int tokbase = b * 3136 + wh * 7 * 56 + ww_ * 7;

    // ---- issue all global loads first (Q,K frags + V rows) ----
    float scale = __expf(fminf(ls[h], 4.6051702f));  // ln(100)
    int4 qf[4], kf[4], vf[4];
    const int4 zero4 = make_int4(0, 0, 0, 0);
#pragma unroll
    for (int t = 0; t < 4; ++t) {
        int i = t * 16 + lr;
        bool valid = (i < 49);
        int tok = tokbase + (i / 7) * 56 + (i % 7);
        const short* base = qkv + (size_t)tok * 384 + h * 32 + lg * 8;
        qf[t] = valid ? *(const int4*)base : zero4;
        kf[t] = valid ? *(const int4*)(base + 128) : zero4;
    }
#pragma unroll
    for (int t = 0; t < 4; ++t) {
        int e = t * 64 + l;          // 0..255; need 196
        int j = e >> 2, dq = e & 3;
        if (j < 49) {
            int tok = tokbase + (j / 7) * 56 + (j % 7);
            vf[t] = *(const int4*)(qkv + (size_t)tok * 384 + 256 + h * 32 + dq * 8);
        } else {
            vf[t] = zero4;
        }
    }

    // ---- normalize Q/K in-register (overlaps V loads in flight) ----
#pragma unroll
    for (int t = 0; t < 4; ++t) {
#pragma unroll
        for (int m = 0; m < 2; ++m) {
            FragU u; u.i4 = m ? kf[t] : qf[t];
            float x[8], ss = 0.f;
#pragma unroll
            for (int e = 0; e < 8; ++e) { x[e] = bf2f(u.u[e]); ss = fmaf(x[e], x[e], ss); }
            ss += __shfl_xor(ss, 16);
            ss += __shfl_xor(ss, 32);
            float inv = 1.0f / fmaxf(sqrtf(ss), 1e-12f);
            if (m == 0) inv *= scale;
#pragma unroll
            for (int e = 0; e < 8; ++e) u.u[e] = (unsigned short)f2bf(x[e] * inv);
            if (m) kf[t] = u.i4; else qf[t] = u.i4;
        }
    }

    // ---- zero Vt pad cols (j=49..63) and scatter V^T into LDS ----
    for (int t = l; t < 480; t += 64) {
        Vt[(t / 15) * 72 + 49 + (t % 15)] = 0;
    }
#pragma unroll
    for (int t = 0; t < 4; ++t) {
        int e = t * 64 + l;
        int j = e >> 2, dq = e & 3;
        if (j < 49) {
            FragU u; u.i4 = vf[t];
#pragma unroll
            for (int ee = 0; ee < 8; ++ee) Vt[(dq * 8 + ee) * 72 + j] = (short)u.u[ee];
        }
    }

    // ---- S^T = Kn @ Qn^T ----
    const f32x4 fz = {0.f, 0.f, 0.f, 0.f};
    f32x4 acc[4][4];
#pragma unroll
    for (int qt = 0; qt < 4; ++qt)
#pragma unroll
        for (int jt = 0; jt < 4; ++jt) acc[qt][jt] = fz;
    __builtin_amdgcn_s_setprio(1);
#pragma unroll
    for (int jt = 0; jt < 4; ++jt) {
        FragU a; a.i4 = kf[jt];
#pragma unroll
        for (int qt = 0; qt < 4; ++qt) {
            FragU bq; bq.i4 = qf[qt];
            acc[qt][jt] = __builtin_amdgcn_mfma_f32_16x16x32_bf16(a.b8, bq.b8, acc[qt][jt], 0, 0, 0);
        }
    }
    __builtin_amdgcn_s_setprio(0);

    // ---- per q-tile: +rpb/mask, softmax, pack P-tile, PV-accumulate ----
    bool edge = (shift != 0) && ((wh == 7) || (ww_ == 7));
    const float* rbase = rpb64 + h * 4096;
    f32x4 oacc[2][4];
#pragma unroll
    for (int mi = 0; mi < 2; ++mi)
#pragma unroll
        for (int ni = 0; ni < 4; ++ni) oacc[mi][ni] = fz;

#pragma unroll
    for (int qt = 0; qt < 4; ++qt) {
        int qi = qt * 16 + lr;
        int qc = (qi < 49) ? qi : 48;
        int rlq = 0, clq = 0;
        if (edge) {
            rlq = (wh == 7) ? ((qc / 7) < 4 ? 1 : 2) : 0;
            clq = (ww_ == 7) ? ((qc % 7) < 4 ? 1 : 2) : 0;
        }
#pragma unroll
        for (int jt = 0; jt < 4; ++jt) {
            float4 rv = *(const float4*)(rbase + qc * 64 + jt * 16 + lg * 4);
            float rr[4] = {rv.x, rv.y, rv.z, rv.w};
#pragma unroll
            for (int r = 0; r < 4; ++r) {
                float v = acc[qt][jt][r] + rr[r];
                if (edge) {
                    int j = jt * 16 + lg * 4 + r;
                    int jc = (j < 49) ? j : 48;
                    int rlk = (wh == 7) ? ((jc / 7) < 4 ? 1 : 2) : 0;
                    int clk = (ww_ == 7) ? ((jc % 7) < 4 ? 1 : 2) : 0;
                    if (rlk != rlq || clk != clq) v -= 100.0f;
                }
                acc[qt][jt][r] = v;
            }
        }
        float m = -1e30f;
#pragma unroll
        for (int jt = 0; jt < 4; ++jt)
#pragma unroll
            for (int r = 0; r < 4; ++r) m = fmaxf(m, acc[qt][jt][r]);
        m = fmaxf(m, __shfl_xor(m, 16));
        m = fmaxf(m, __shfl_xor(m, 32));
        float s = 0.f;
#pragma unroll
        for (int jt = 0; jt < 4; ++jt)
#pragma unroll
            for (int r = 0; r < 4; ++r) {
                float p = __expf(acc[qt][jt][r] - m);
                acc[qt][jt][r] = p;
                s += p;
            }
        s += __shfl_xor(s, 16);
        s += __shfl_xor(s, 32);
        float inv = 1.0f / s;
        // pack this q-tile's P rows: Pt[lr][j]
#pragma unroll
        for (int jt = 0; jt < 4; ++jt) {
            unsigned lo = (unsigned)(unsigned short)f2bf(acc[qt][jt][0] * inv) |
                          ((unsigned)(unsigned short)f2bf(acc[qt][jt][1] * inv) << 16);
            unsigned hi = (unsigned)(unsigned short)f2bf(acc[qt][jt][2] * inv) |
                          ((unsigned)(unsigned short)f2bf(acc[qt][jt][3] * inv) << 16);
            *(int2*)&Pt[lr * 72 + jt * 16 + lg * 4] = make_int2((int)lo, (int)hi);
        }
        // PV for output q-tile qt (wave-private LDS; compiler inserts lgkmcnt)
        __builtin_amdgcn_s_setprio(1);
#pragma unroll
        for (int kc = 0; kc < 2; ++kc) {
            FragU pb;
            pb.i4 = *(const int4*)&Pt[lr * 72 + kc * 32 + lg * 8];
#pragma unroll
            for (int mi = 0; mi < 2; ++mi) {
                FragU va;
                va.i4 = *(const int4*)&Vt[(mi * 16 + lr) * 72 + kc * 32 + lg * 8];
                oacc[mi][qt] = __builtin_amdgcn_mfma_f32_16x16x32_bf16(
                    va.b8, pb.b8, oacc[mi][qt], 0, 0, 0);
            }
        }
        __builtin_amdgcn_s_setprio(0);
    }

    // store: qrow=ni*16+lr, d=mi*16+lg*4+r
#pragma unroll
    for (int ni = 0; ni < 4; ++ni) {
        int qrow = ni * 16 + lr;
        if (qrow < 49) {
            int tok = tokbase + (qrow / 7) * 56 + (qrow % 7);
#pragma unroll
            for (int mi = 0; mi < 2; ++mi) {
                unsigned lo = (unsigned)(unsigned short)f2bf(oacc[mi][ni][0]) |
                              ((unsigned)(unsigned short)f2bf(oacc[mi][ni][1]) << 16);
                unsigned hi = (unsigned)(unsigned short)f2bf(oacc[mi][ni][2]) |
                              ((unsigned)(unsigned short)f2bf(oacc[mi][ni][3]) << 16);
                *(int2*)&aout[(size_t)tok * 128 + h * 32 + mi * 16 + lg * 4] =
                    make_int2((int)lo, (int)hi);
            }
        }
    }
}

// ------------- PatchMerging gather + LN -> bf16 rows [25088][512] ----------
__global__ __launch_bounds__(256) void k_pmln(
    const float* __restrict__ x, const float* __restrict__ g,
    const float* __restrict__ bt, short* __restrict__ outb) {
    int m2 = blockIdx.x * 4 + (threadIdx.x >> 6);
    int l = threadIdx.x & 63;
    int b = m2 / 784, r = m2 % 784;
    int h2 = r / 28, w2 = r % 28;
    int q0 = l * 8;
    int i2 = q0 >> 8, j2 = (q0 >> 7) & 1, c = q0 & 127;
    const float* src = x + (size_t)((b * 56 + 2 * h2 + i2) * 56 + 2 * w2 + j2) * 128 + c;
    float4 f0 = *(const float4*)src;
    float4 f1 = *(const float4*)(src + 4);
    float v[8] = {f0.x, f0.y, f0.z, f0.w, f1.x, f1.y, f1.z, f1.w};
    float s1 = 0.f, s2 = 0.f;
#pragma unroll
    for (int e = 0; e < 8; ++e) { s1 += v[e]; s2 = fmaf(v[e], v[e], s2); }
#pragma unroll
    for (int off = 32; off >= 1; off >>= 1) {
        s1 += __shfl_xor(s1, off);
        s2 += __shfl_xor(s2, off);
    }
    float mean = s1 * (1.0f / 512.0f);
    float var = s2 * (1.0f / 512.0f) - mean * mean;
    float rstd = rsqrtf(var + 1e-5f);
    union { int4 i4; short s8[8]; } u;
#pragma unroll
    for (int e = 0; e < 8; ++e)
        u.s8[e] = f2bf((v[e] - mean) * rstd * g[q0 + e] + bt[q0 + e]);
    *(int4*)(outb + (size_t)m2 * 512 + q0) = u.i4;
}

// ---------------------------------------------------------------------------
extern "C" void kernel_launch(void* const* d_in, const int* in_sizes, int n_in,
                              void* d_out, int out_size, void* d_ws, size_t ws_size,
                              hipStream_t stream) {
    const float* x_in   = (const float*)d_in[0];
    const float* qkv_w  = (const float*)d_in[1];
    const float* q_bias = (const float*)d_in[2];
    const float* v_bias = (const float*)d_in[3];
    const float* lscale = (const float*)d_in[4];
    const float* cpb_w1 = (const float*)d_in[5];
    const float* cpb_b1 = (const float*)d_in[6];
    const float* cpb_w2 = (const float*)d_in[7];
    const float* proj_w = (const float*)d_in[8];
    const float* proj_b = (const float*)d_in[9];
    const float* n1g    = (const float*)d_in[10];
    const float* n1b    = (const float*)d_in[11];
    const float* mw1    = (const float*)d_in[12];
    const float* mb1    = (const float*)d_in[13];
    const float* mw2    = (const float*)d_in[14];
    const float* mb2    = (const float*)d_in[15];
    const float* n2g    = (const float*)d_in[16];
    const float* n2b    = (const float*)d_in[17];
    const float* pmg    = (const float*)d_in[18];
    const float* pmb    = (const float*)d_in[19];
    const float* pmw    = (const float*)d_in[20];
    float* out = (float*)d_out;

    float* wsf     = (float*)d_ws;
    float* xcur    = wsf;
    float* R1      = wsf + (size_t)12845056;
    short* qkvb    = (short*)R1;
    short* attnout = (short*)(R1 + (size_t)19267584);   // kTok*128 bf16
    short* hid     = (short*)R1;
    short* pmin    = (short*)R1;                        // 25088*512 bf16
    short* xb      = (short*)(R1 + (size_t)25690112);   // kTok*128 bf16
    float* wtail   = R1 + (size_t)38535168;
    short* wqkvb   = (short*)wtail;          // 49,152 bf16
    short* wprojb  = wqkvb + 49152;          // 16,384
    short* wm1b    = wprojb + 16384;         // 65,536
    short* wm2b    = wm1b + 65536;           // 65,536
    short* wpmb    = wm2b + 65536;           // 131,072
    float* out169  = wtail + 163840;
    float* rpb64   = out169 + 704;

    k_cvtx<<<6272, 256, 0, stream>>>(x_in, xb);

    for (int i = 0; i < 2; ++i) {
        int shift = i ? 3 : 0;
        const float* xi = (i == 0) ? x_in : xcur;
        k_cpb<<<169, 256, 0, stream>>>(cpb_w1 + i * 1024, cpb_b1 + i * 512,
                                       cpb_w2 + i * 2048, out169);
        k_rpb<<<64, 256, 0, stream>>>(out169, rpb64);
        k_cvtw<<<24, 256, 0, stream>>>(qkv_w + i * 49152, wqkvb, 16, 384);
        k_cvtw<<<8, 256, 0, stream>>>(proj_w + i * 16384, wprojb, 16, 128);
        k_cvtw<<<32, 256, 0, stream>>>(mw1 + i * 65536, wm1b, 16, 512);
        k_cvtw<<<32, 256, 0, stream>>>(mw2 + i * 65536, wm2b, 64, 128);

        k_gemm<128, 1, 6><<<4704, 256, 0, stream>>>(
            xb, wqkvb, q_bias + i * 128, v_bias + i * 128, qkvb, 384, shift);
        k_attn<<<2048, 256, 0, stream>>>(
            qkvb, rpb64, lscale + i * 4, attnout, shift);
        k_gemm_ln<128><<<1568, 256, 0, stream>>>(
            attnout, wprojb, proj_b + i * 128, n1g + i * 128, n1b + i * 128,
            xi, xcur, xb, shift);
        k_gemm<128, 2, 8><<<6272, 256, 0, stream>>>(
            xb, wm1b, mb1 + i * 512, nullptr, hid, 512, 0);
        k_gemm_ln<512><<<1568, 256, 0, stream>>>(
            hid, wm2b, mb2 + i * 128, n2g + i * 128, n2b + i * 128,
            xcur, xcur, xb, 0);
    }
    k_cvtw<<<64, 256, 0, stream>>>(pmw, wpmb, 64, 256);
    k_pmln<<<6272, 256, 0, stream>>>(xcur, pmg, pmb, pmin);
    k_gemm<512, 0, 4><<<784, 256, 0, stream>>>(
        pmin, wpmb, nullptr, nullptr, out, 256, 0);
}

// Round 8
// 466.960 us; speedup vs baseline: 1.0472x; 1.0472x over previous
//
#include <hip/hip_runtime.h>
#include <math.h>

// ---------------------------------------------------------------------------
// SwinV2 stage: B=32, H=W=56, C=128, NH=4, hd=32, WS=7, N=49, DEPTH=2, shift=3
// Round 8: attn VALU/register diet — deferred cosine-normalization (scale S
// after raw-QK^T MFMA), per-q-tile S lifetime (acc 64->16 regs), cvt_pk
// bf16 packing. GEMMs unchanged from R7.
// ---------------------------------------------------------------------------

namespace {
constexpr int kTok = 32 * 56 * 56;   // 100352 tokens
}

typedef __attribute__((ext_vector_type(8))) short bf16x8;
typedef __attribute__((ext_vector_type(4))) float f32x4;

union FragU {
    int4 i4;
    bf16x8 b8;
    unsigned short u[8];
};

__device__ __forceinline__ short f2bf(float f) {
    unsigned u = __float_as_uint(f);
    return (short)((u + 0x7FFFu + ((u >> 16) & 1u)) >> 16);
}
__device__ __forceinline__ float bf2f(unsigned short u) {
    return __uint_as_float(((unsigned)u) << 16);
}
__device__ __forceinline__ unsigned cvt_pk_bf16(float a, float b) {
    unsigned r;
    asm("v_cvt_pk_bf16_f32 %0, %1, %2" : "=v"(r) : "v"(a), "v"(b));
    return r;
}
__device__ __forceinline__ float gelu_f(float x) {
    return 0.5f * x * (1.0f + erff(x * 0.70710678118654752f));
}

// --------------------------- CPB MLP (tiny) --------------------------------
__global__ __launch_bounds__(256) void k_cpb(
    const float* __restrict__ w1, const float* __restrict__ b1,
    const float* __restrict__ w2, float* __restrict__ out169) {
    int t = blockIdx.x;  // 0..168
    int ia = t / 13, ib = t % 13;
    float r0 = (float)(ia - 6) * (8.0f / 6.0f);
    float s0 = (r0 > 0.f) ? 1.f : (r0 < 0.f ? -1.f : 0.f);
    float t0 = s0 * log2f(fabsf(r0) + 1.0f) * (1.0f / 3.0f);
    float r1 = (float)(ib - 6) * (8.0f / 6.0f);
    float s1 = (r1 > 0.f) ? 1.f : (r1 < 0.f ? -1.f : 0.f);
    float t1 = s1 * log2f(fabsf(r1) + 1.0f) * (1.0f / 3.0f);

    int tid = threadIdx.x;
    float p0 = 0, p1 = 0, p2 = 0, p3 = 0;
    for (int c = tid; c < 512; c += 256) {
        float hv = fmaxf(t0 * w1[c] + t1 * w1[512 + c] + b1[c], 0.0f);
        p0 += hv * w2[c * 4 + 0];
        p1 += hv * w2[c * 4 + 1];
        p2 += hv * w2[c * 4 + 2];
        p3 += hv * w2[c * 4 + 3];
    }
    __shared__ float red[256][4];
    red[tid][0] = p0; red[tid][1] = p1; red[tid][2] = p2; red[tid][3] = p3;
    __syncthreads();
    for (int s = 128; s > 0; s >>= 1) {
        if (tid < s) {
            red[tid][0] += red[tid + s][0];
            red[tid][1] += red[tid + s][1];
            red[tid][2] += red[tid + s][2];
            red[tid][3] += red[tid + s][3];
        }
        __syncthreads();
    }
    if (tid < 4) out169[t * 4 + tid] = red[0][tid];
}

// rpb64[h][qrow64][krow64]; krow>=49 -> -30000 (k-pad baked in)
__global__ void k_rpb(const float* __restrict__ out169, float* __restrict__ rpb64) {
    int e = blockIdx.x * 256 + threadIdx.x;
    if (e >= 4 * 64 * 64) return;
    int h = e >> 12, r = e & 4095;
    int i = r >> 6, j = r & 63;
    float val;
    if (j >= 49) {
        val = -30000.0f;
    } else if (i >= 49) {
        val = 0.0f;
    } else {
        int dp = i / 7 - j / 7 + 6;
        int dq = i % 7 - j % 7 + 6;
        float v = out169[(dp * 13 + dq) * 4 + h];
        val = 16.0f / (1.0f + expf(-v));
    }
    rpb64[e] = val;
}

// ------------------- weight fp32 -> bf16 tiled image -----------------------
// Logical slot (nt*Kb + kb)*64 + nn holds W[kb*8+e][nt*64+nn], e=0..7.
// Stored at physical nn' = (nn & ~3) | ((nn ^ kb) & 3).
__global__ __launch_bounds__(256) void k_cvtw(
    const float* __restrict__ W, short* __restrict__ Wb, int Kb, int N) {
    int slt = blockIdx.x * 256 + threadIdx.x;
    if (slt >= Kb * N) return;
    int nn = slt & 63;
    int tmp = slt >> 6;
    int kb = tmp % Kb;
    int nt = tmp / Kb;
    int n = nt * 64 + nn;
    int k0 = kb * 8;
    union { int4 i4; short s8[8]; } u;
#pragma unroll
    for (int e = 0; e < 8; ++e) u.s8[e] = f2bf(W[(size_t)(k0 + e) * N + n]);
    int nns = (nn & ~3) | ((nn ^ kb) & 3);
    *(int4*)(Wb + (((size_t)tmp) * 64 + nns) * 8) = u.i4;
}

// ------------------- activation fp32 -> bf16 rows --------------------------
__global__ __launch_bounds__(256) void k_cvtx(
    const float* __restrict__ x, short* __restrict__ xb) {
    size_t e = ((size_t)blockIdx.x * 256 + threadIdx.x) * 8;
    const float* src = x + e;
    float4 f0 = *(const float4*)src;
    float4 f1 = *(const float4*)(src + 4);
    union { int4 i4; short s8[8]; } u;
    u.s8[0] = f2bf(f0.x); u.s8[1] = f2bf(f0.y);
    u.s8[2] = f2bf(f0.z); u.s8[3] = f2bf(f0.w);
    u.s8[4] = f2bf(f1.x); u.s8[5] = f2bf(f1.y);
    u.s8[6] = f2bf(f1.z); u.s8[7] = f2bf(f1.w);
    *(int4*)(xb + e) = u.i4;
}

// --------------------------- MFMA GEMM (bf16 A) ----------------------------
template <int K, int EPI, int NT>
__global__ __launch_bounds__(256) void k_gemm(
    const short* __restrict__ Ain, const short* __restrict__ Wb,
    const float* __restrict__ bias0, const float* __restrict__ bias1,
    void* __restrict__ Out, int ostride, int shift) {
    constexpr int Kb = K / 8;
    constexpr int NC = K / 128;
    __shared__ int4 As4[2048];  // [16 kb][128 m], XOR-swizzled (8-wide)
    __shared__ int4 Ws4[1024];  // [16 kb][64 nn], XOR-swizzled (4-wide, in image)
    int tid = threadIdx.x;
    int nwg = gridDim.x;
    int chunk = nwg >> 3;
    int lid = (blockIdx.x & 7) * chunk + (blockIdx.x >> 3);
    int mt = lid / NT, nt = lid - mt * NT;
    int mb = mt * 128;
    int w = tid >> 6, l = tid & 63, lr = l & 15, lg = l >> 4;
    const f32x4 fz = {0.f, 0.f, 0.f, 0.f};
    f32x4 acc[2][4];
#pragma unroll
    for (int mi = 0; mi < 2; ++mi)
#pragma unroll
        for (int ni = 0; ni < 4; ++ni) acc[mi][ni] = fz;

    for (int c = 0; c < NC; ++c) {
        if (c) __syncthreads();
#pragma unroll
        for (int it = 0; it < 8; ++it) {
            int s = it * 256 + tid;
            int m = s >> 4, kb = s & 15;
            int gm = mb + m;
            if (EPI == 1 && shift) {
                int b = gm / 3136, r = gm % 3136;
                int hh = r / 56 + shift; if (hh >= 56) hh -= 56;
                int ww = r % 56 + shift; if (ww >= 56) ww -= 56;
                gm = b * 3136 + hh * 56 + ww;
            }
            int slot = kb * 128 + ((m & ~7) | ((m ^ kb) & 7));
            As4[slot] = *(const int4*)(Ain + (size_t)gm * K + c * 128 + kb * 8);
        }
        {
            const int4* wsrc = (const int4*)(Wb + ((size_t)nt * Kb + c * 16) * 64 * 8);
#pragma unroll
            for (int it = 0; it < 4; ++it) Ws4[it * 256 + tid] = wsrc[it * 256 + tid];
        }
        __syncthreads();
#pragma unroll
        for (int kk = 0; kk < 4; ++kk) {
            int kbl = kk * 4 + lg;
            int m0 = w * 32 + lr;
            bf16x8 a0 = *(const bf16x8*)&As4[kbl * 128 + ((m0 & ~7) | ((m0 ^ kbl) & 7))];
            int m1 = m0 + 16;
            bf16x8 a1 = *(const bf16x8*)&As4[kbl * 128 + ((m1 & ~7) | ((m1 ^ kbl) & 7))];
#pragma unroll
            for (int ni = 0; ni < 4; ++ni) {
                int nn = lr + 16 * ni;
                bf16x8 bfr = *(const bf16x8*)&Ws4[kbl * 64 + ((nn & ~3) | ((nn ^ kbl) & 3))];
                acc[0][ni] = __builtin_amdgcn_mfma_f32_16x16x32_bf16(a0, bfr, acc[0][ni], 0, 0, 0);
                acc[1][ni] = __builtin_amdgcn_mfma_f32_16x16x32_bf16(a1, bfr, acc[1][ni], 0, 0, 0);
            }
        }
    }
#pragma unroll
    for (int ni = 0; ni < 4; ++ni) {
        int col = nt * 64 + ni * 16 + lr;
        float bv = 0.f;
        if (EPI == 1) bv = (col < 128) ? bias0[col] : ((col < 256) ? 0.f : bias1[col - 256]);
        if (EPI == 2) bv = bias0[col];
#pragma unroll
        for (int mi = 0; mi < 2; ++mi) {
#pragma unroll
            for (int r = 0; r < 4; ++r) {
                int row = mb + w * 32 + mi * 16 + lg * 4 + r;
                float v = acc[mi][ni][r] + bv;
                if (EPI == 0) {
                    ((float*)Out)[(size_t)row * ostride + col] = v;
                } else if (EPI == 1) {
                    ((short*)Out)[(size_t)row * 384 + col] = f2bf(v);
                } else {
                    ((short*)Out)[(size_t)row * 512 + col] = f2bf(gelu_f(v));
                }
            }
        }
    }
}

// ------------- MFMA GEMM + bias + LN + residual (+roll-back) ---------------
template <int K>
__global__ __launch_bounds__(256) void k_gemm_ln(
    const short* __restrict__ Ain, const short* __restrict__ Wb,
    const float* __restrict__ bias, const float* __restrict__ g,
    const float* __restrict__ bt, const float* __restrict__ resid,
    float* __restrict__ xout, short* __restrict__ xoutb, int shift) {
    constexpr int Kb = K / 8;
    constexpr int NC = K / 128;
    __shared__ int4 As4[1024];  // [16 kb][64 m]
    __shared__ int4 Ws4[2048];  // [2 ntw][16 kb][64 nn]
    int tid = threadIdx.x;
    int mb = blockIdx.x * 64;
    int w = tid >> 6, l = tid & 63, lr = l & 15, lg = l >> 4;
    const f32x4 fz = {0.f, 0.f, 0.f, 0.f};
    f32x4 acc[8];
#pragma unroll
    for (int ni = 0; ni < 8; ++ni) acc[ni] = fz;

    for (int c = 0; c < NC; ++c) {
        if (c) __syncthreads();
#pragma unroll
        for (int it = 0; it < 4; ++it) {
            int s = it * 256 + tid;
            int m = s >> 4, kb = s & 15;
            int slot = kb * 64 + ((m & ~7) | ((m ^ kb) & 7));
            As4[slot] = *(const int4*)(Ain + (size_t)(mb + m) * K + c * 128 + kb * 8);
        }
        {
            const int4* w0 = (const int4*)(Wb + ((size_t)(c * 16)) * 64 * 8);
            const int4* w1 = (const int4*)(Wb + ((size_t)(Kb + c * 16)) * 64 * 8);
#pragma unroll
            for (int it = 0; it < 4; ++it) {
                Ws4[it * 256 + tid] = w0[it * 256 + tid];
                Ws4[1024 + it * 256 + tid] = w1[it * 256 + tid];
            }
        }
        __syncthreads();
#pragma unroll
        for (int kk = 0; kk < 4; ++kk) {
            int kbl = kk * 4 + lg;
            int m0 = w * 16 + lr;
            bf16x8 a0 = *(const bf16x8*)&As4[kbl * 64 + ((m0 & ~7) | ((m0 ^ kbl) & 7))];
#pragma unroll
            for (int ni = 0; ni < 8; ++ni) {
                int nn = lr + 16 * (ni & 3);
                bf16x8 bfr = *(const bf16x8*)&Ws4[(ni >> 2) * 1024 + kbl * 64 +
                                                  ((nn & ~3) | ((nn ^ kbl) & 3))];
                acc[ni] = __builtin_amdgcn_mfma_f32_16x16x32_bf16(a0, bfr, acc[ni], 0, 0, 0);
            }
        }
    }
    float bv[8], gv[8], btv[8];
#pragma unroll
    for (int ni = 0; ni < 8; ++ni) {
        int col = ni * 16 + lr;
        bv[ni] = bias[col]; gv[ni] = g[col]; btv[ni] = bt[col];
    }
#pragma unroll
    for (int r = 0; r < 4; ++r) {
        int row = mb + w * 16 + lg * 4 + r;
        float v[8];
        float s1 = 0.f, s2 = 0.f;
#pragma unroll
        for (int ni = 0; ni < 8; ++ni) {
            v[ni] = acc[ni][r] + bv[ni];
            s1 += v[ni];
            s2 = fmaf(v[ni], v[ni], s2);
        }
#pragma unroll
        for (int off = 8; off >= 1; off >>= 1) {
            s1 += __shfl_xor(s1, off);
            s2 += __shfl_xor(s2, off);
        }
        float mean = s1 * (1.0f / 128.0f);
        float var = s2 * (1.0f / 128.0f) - mean * mean;
        float rstd = rsqrtf(var + 1e-5f);
        int mo = row;
        if (shift) {
            int b = row / 3136, rr = row % 3136;
            int hh = rr / 56 + shift; if (hh >= 56) hh -= 56;
            int ww = rr % 56 + shift; if (ww >= 56) ww -= 56;
            mo = b * 3136 + hh * 56 + ww;
        }
        size_t base = (size_t)mo * 128;
#pragma unroll
        for (int ni = 0; ni < 8; ++ni) {
            int col = ni * 16 + lr;
            float o = resid[base + col] + (v[ni] - mean) * rstd * gv[ni] + btv[ni];
            xout[base + col] = o;
            xoutb[base + col] = f2bf(o);
        }
    }
}

// --------------------------- MFMA windowed attention -----------------------
// grid 2048 (one block per window), 4 waves = 4 heads, wave-private LDS.
// Raw-QK^T then post-scale by invq*invk*logit_scale (algebraically identical
// to cosine attention). Per-q-tile S lifetime keeps acc regs at 16.
__global__ __launch_bounds__(256) void k_attn(
    const short* __restrict__ qkv, const float* __restrict__ rpb64,
    const float* __restrict__ ls, short* __restrict__ aout, int shift) {
    __shared__ short lds[4 * 3584];
    int wid = blockIdx.x;
    int b = wid >> 6, wrem = wid & 63;
    int wh = wrem >> 3, ww_ = wrem & 7;
    int h = threadIdx.x >> 6;
    int l = threadIdx.x & 63, lr = l & 15, lg = l >> 4;
    short* Pt = lds + h * 3584;              // [16 qrow][72]
    short* Vt = Pt + 1152;                   // [32 d][72]
    float* invks = (float*)(Vt + 2304);      // [64] 1/||k_j||
    int tokbase = b * 3136 + wh * 7 * 56 + ww_ * 7;

    float scale = __expf(fminf(ls[h], 4.6051702f));  // ln(100)
    int4 qf[4], kf[4], vf[4];
    const int4 zero4 = make_int4(0, 0, 0, 0);
#pragma unroll
    for (int t = 0; t < 4; ++t) {
        int i = t * 16 + lr;
        bool valid = (i < 49);
        int tok = tokbase + (i / 7) * 56 + (i % 7);
        const short* base = qkv + (size_t)tok * 384 + h * 32 + lg * 8;
        qf[t] = valid ? *(const int4*)base : zero4;
        kf[t] = valid ? *(const int4*)(base + 128) : zero4;
    }
#pragma unroll
    for (int t = 0; t < 4; ++t) {
        int e = t * 64 + l;
        int j = e >> 2, dq = e & 3;
        if (j < 49) {
            int tok = tokbase + (j / 7) * 56 + (j % 7);
            vf[t] = *(const int4*)(qkv + (size_t)tok * 384 + 256 + h * 32 + dq * 8);
        } else {
            vf[t] = zero4;
        }
    }

    // ---- row norms (no repack): invq per-lane, invk via small LDS table ----
    float invq[4];
#pragma unroll
    for (int t = 0; t < 4; ++t) {
        {
            FragU u; u.i4 = qf[t];
            float ss = 0.f;
#pragma unroll
            for (int e = 0; e < 8; ++e) { float x = bf2f(u.u[e]); ss = fmaf(x, x, ss); }
            ss += __shfl_xor(ss, 16);
            ss += __shfl_xor(ss, 32);
            invq[t] = scale / fmaxf(sqrtf(ss), 1e-12f);
        }
        {
            FragU u; u.i4 = kf[t];
            float ss = 0.f;
#pragma unroll
            for (int e = 0; e < 8; ++e) { float x = bf2f(u.u[e]); ss = fmaf(x, x, ss); }
            ss += __shfl_xor(ss, 16);
            ss += __shfl_xor(ss, 32);
            float ik = 1.0f / fmaxf(sqrtf(ss), 1e-12f);
            if (l < 16) invks[t * 16 + l] = ik;   // rows>=49 benign (raw S = 0)
        }
    }

    // ---- zero Vt pad cols and scatter V^T into LDS ----
    for (int t = l; t < 480; t += 64) {
        Vt[(t / 15) * 72 + 49 + (t % 15)] = 0;
    }
#pragma unroll
    for (int t = 0; t < 4; ++t) {
        int e = t * 64 + l;
        int j = e >> 2, dq = e & 3;
        if (j < 49) {
            FragU u; u.i4 = vf[t];
#pragma unroll
            for (int ee = 0; ee < 8; ++ee) Vt[(dq * 8 + ee) * 72 + j] = (short)u.u[ee];
        }
    }

    // invk fragments for S-scaling: element (jt, r) uses invks[jt*16+lg*4+r]
    float ika[4][4];
#pragma unroll
    for (int jt = 0; jt < 4; ++jt) {
        float4 v4 = *(const float4*)&invks[jt * 16 + lg * 4];
        ika[jt][0] = v4.x; ika[jt][1] = v4.y; ika[jt][2] = v4.z; ika[jt][3] = v4.w;
    }

    bool edge = (shift != 0) && ((wh == 7) || (ww_ == 7));
    const float* rbase = rpb64 + h * 4096;
    const f32x4 fz = {0.f, 0.f, 0.f, 0.f};
    f32x4 oacc[2][4];
#pragma unroll
    for (int mi = 0; mi < 2; ++mi)
#pragma unroll
        for (int ni = 0; ni < 4; ++ni) oacc[mi][ni] = fz;

#pragma unroll
    for (int qt = 0; qt < 4; ++qt) {
        // S^T tile: col = qrow = qt*16+lr, row = krow = jt*16+lg*4+r
        f32x4 at[4];
        __builtin_amdgcn_s_setprio(1);
#pragma unroll
        for (int jt = 0; jt < 4; ++jt) {
            FragU a; a.i4 = kf[jt];
            FragU bq; bq.i4 = qf[qt];
            at[jt] = __builtin_amdgcn_mfma_f32_16x16x32_bf16(a.b8, bq.b8, fz, 0, 0, 0);
        }
        __builtin_amdgcn_s_setprio(0);

        float iq = invq[qt];
        int qi = qt * 16 + lr;
        int qc = (qi < 49) ? qi : 48;
        int rlq = 0, clq = 0;
        if (edge) {
            rlq = (wh == 7) ? ((qc / 7) < 4 ? 1 : 2) : 0;
            clq = (ww_ == 7) ? ((qc % 7) < 4 ? 1 : 2) : 0;
        }
#pragma unroll
        for (int jt = 0; jt < 4; ++jt) {
            float4 rv = *(const float4*)(rbase + qc * 64 + jt * 16 + lg * 4);
            float rr[4] = {rv.x, rv.y, rv.z, rv.w};
#pragma unroll
            for (int r = 0; r < 4; ++r) {
                float v = fmaf(at[jt][r] * ika[jt][r], iq, rr[r]);
                if (edge) {
                    int j = jt * 16 + lg * 4 + r;
                    int jc = (j < 49) ? j : 48;
                    int rlk = (wh == 7) ? ((jc / 7) < 4 ? 1 : 2) : 0;
                    int clk = (ww_ == 7) ? ((jc % 7) < 4 ? 1 : 2) : 0;
                    if (rlk != rlq || clk != clq) v -= 100.0f;
                }
                at[jt][r] = v;
            }
        }
        float m = -1e30f;
#pragma unroll
        for (int jt = 0; jt < 4; ++jt)
#pragma unroll
            for (int r = 0; r < 4; ++r) m = fmaxf(m, at[jt][r]);
        m = fmaxf(m, __shfl_xor(m, 16));
        m = fmaxf(m, __shfl_xor(m, 32));
        float s = 0.f;
#pragma unroll
        for (int jt = 0; jt < 4; ++jt)
#pragma unroll
            for (int r = 0; r < 4; ++r) {
                float p = __expf(at[jt][r] - m);
                at[jt][r] = p;
                s += p;
            }
        s += __shfl_xor(s, 16);
        s += __shfl_xor(s, 32);
        float inv = 1.0f / s;
        // pack this q-tile's P rows: Pt[lr][j]
#pragma unroll
        for (int jt = 0; jt < 4; ++jt) {
            unsigned lo = cvt_pk_bf16(at[jt][0] * inv, at[jt][1] * inv);
            unsigned hi = cvt_pk_bf16(at[jt][2] * inv, at[jt][3] * inv);
            *(int2*)&Pt[lr * 72 + jt * 16 + lg * 4] = make_int2((int)lo, (int)hi);
        }
        // PV for output q-tile qt (wave-private LDS)
        __builtin_amdgcn_s_setprio(1);
#pragma unroll
        for (int kc = 0; kc < 2; ++kc) {
            FragU pb;
            pb.i4 = *(const int4*)&Pt[lr * 72 + kc * 32 + lg * 8];
#pragma unroll
            for (int mi = 0; mi < 2; ++mi) {
                FragU va;
                va.i4 = *(const int4*)&Vt[(mi * 16 + lr) * 72 + kc * 32 + lg * 8];
                oacc[mi][qt] = __builtin_amdgcn_mfma_f32_16x16x32_bf16(
                    va.b8, pb.b8, oacc[mi][qt], 0, 0, 0);
            }
        }
        __builtin_amdgcn_s_setprio(0);
    }

    // store: qrow=ni*16+lr, d=mi*16+lg*4+r
#pragma unroll
    for (int ni = 0; ni < 4; ++ni) {
        int qrow = ni * 16 + lr;
        if (qrow < 49) {
            int tok = tokbase + (qrow / 7) * 56 + (qrow % 7);
#pragma unroll
            for (int mi = 0; mi < 2; ++mi) {
                unsigned lo = cvt_pk_bf16(oacc[mi][ni][0], oacc[mi][ni][1]);
                unsigned hi = cvt_pk_bf16(oacc[mi][ni][2], oacc[mi][ni][3]);
                *(int2*)&aout[(size_t)tok * 128 + h * 32 + mi * 16 + lg * 4] =
                    make_int2((int)lo, (int)hi);
            }
        }
    }
}

// ------------- PatchMerging gather + LN -> bf16 rows [25088][512] ----------
__global__ __launch_bounds__(256) void k_pmln(
    const float* __restrict__ x, const float* __restrict__ g,
    const float* __restrict__ bt, short* __restrict__ outb) {
    int m2 = blockIdx.x * 4 + (threadIdx.x >> 6);
    int l = threadIdx.x & 63;
    int b = m2 / 784, r = m2 % 784;
    int h2 = r / 28, w2 = r % 28;
    int q0 = l * 8;
    int i2 = q0 >> 8, j2 = (q0 >> 7) & 1, c = q0 & 127;
    const float* src = x + (size_t)((b * 56 + 2 * h2 + i2) * 56 + 2 * w2 + j2) * 128 + c;
    float4 f0 = *(const float4*)src;
    float4 f1 = *(const float4*)(src + 4);
    float v[8] = {f0.x, f0.y, f0.z, f0.w, f1.x, f1.y, f1.z, f1.w};
    float s1 = 0.f, s2 = 0.f;
#pragma unroll
    for (int e = 0; e < 8; ++e) { s1 += v[e]; s2 = fmaf(v[e], v[e], s2); }
#pragma unroll
    for (int off = 32; off >= 1; off >>= 1) {
        s1 += __shfl_xor(s1, off);
        s2 += __shfl_xor(s2, off);
    }
    float mean = s1 * (1.0f / 512.0f);
    float var = s2 * (1.0f / 512.0f) - mean * mean;
    float rstd = rsqrtf(var + 1e-5f);
    union { int4 i4; short s8[8]; } u;
#pragma unroll
    for (int e = 0; e < 8; ++e)
        u.s8[e] = f2bf((v[e] - mean) * rstd * g[q0 + e] + bt[q0 + e]);
    *(int4*)(outb + (size_t)m2 * 512 + q0) = u.i4;
}

// ---------------------------------------------------------------------------
extern "C" void kernel_launch(void* const* d_in, const int* in_sizes, int n_in,
                              void* d_out, int out_size, void* d_ws, size_t ws_size,
                              hipStream_t stream) {
    const float* x_in   = (const float*)d_in[0];
    const float* qkv_w  = (const float*)d_in[1];
    const float* q_bias = (const float*)d_in[2];
    const float* v_bias = (const float*)d_in[3];
    const float* lscale = (const float*)d_in[4];
    const float* cpb_w1 = (const float*)d_in[5];
    const float* cpb_b1 = (const float*)d_in[6];
    const float* cpb_w2 = (const float*)d_in[7];
    const float* proj_w = (const float*)d_in[8];
    const float* proj_b = (const float*)d_in[9];
    const float* n1g    = (const float*)d_in[10];
    const float* n1b    = (const float*)d_in[11];
    const float* mw1    = (const float*)d_in[12];
    const float* mb1    = (const float*)d_in[13];
    const float* mw2    = (const float*)d_in[14];
    const float* mb2    = (const float*)d_in[15];
    const float* n2g    = (const float*)d_in[16];
    const float* n2b    = (const float*)d_in[17];
    const float* pmg    = (const float*)d_in[18];
    const float* pmb    = (const float*)d_in[19];
    const float* pmw    = (const float*)d_in[20];
    float* out = (float*)d_out;

    float* wsf     = (float*)d_ws;
    float* xcur    = wsf;
    float* R1      = wsf + (size_t)12845056;
    short* qkvb    = (short*)R1;
    short* attnout = (short*)(R1 + (size_t)19267584);   // kTok*128 bf16
    short* hid     = (short*)R1;
    short* pmin    = (short*)R1;                        // 25088*512 bf16
    short* xb      = (short*)(R1 + (size_t)25690112);   // kTok*128 bf16
    float* wtail   = R1 + (size_t)38535168;
    short* wqkvb   = (short*)wtail;          // 49,152 bf16
    short* wprojb  = wqkvb + 49152;          // 16,384
    short* wm1b    = wprojb + 16384;         // 65,536
    short* wm2b    = wm1b + 65536;           // 65,536
    short* wpmb    = wm2b + 65536;           // 131,072
    float* out169  = wtail + 163840;
    float* rpb64   = out169 + 704;

    k_cvtx<<<6272, 256, 0, stream>>>(x_in, xb);

    for (int i = 0; i < 2; ++i) {
        int shift = i ? 3 : 0;
        const float* xi = (i == 0) ? x_in : xcur;
        k_cpb<<<169, 256, 0, stream>>>(cpb_w1 + i * 1024, cpb_b1 + i * 512,
                                       cpb_w2 + i * 2048, out169);
        k_rpb<<<64, 256, 0, stream>>>(out169, rpb64);
        k_cvtw<<<24, 256, 0, stream>>>(qkv_w + i * 49152, wqkvb, 16, 384);
        k_cvtw<<<8, 256, 0, stream>>>(proj_w + i * 16384, wprojb, 16, 128);
        k_cvtw<<<32, 256, 0, stream>>>(mw1 + i * 65536, wm1b, 16, 512);
        k_cvtw<<<32, 256, 0, stream>>>(mw2 + i * 65536, wm2b, 64, 128);

        k_gemm<128, 1, 6><<<4704, 256, 0, stream>>>(
            xb, wqkvb, q_bias + i * 128, v_bias + i * 128, qkvb, 384, shift);
        k_attn<<<2048, 256, 0, stream>>>(
            qkvb, rpb64, lscale + i * 4, attnout, shift);
        k_gemm_ln<128><<<1568, 256, 0, stream>>>(
            attnout, wprojb, proj_b + i * 128, n1g + i * 128, n1b + i * 128,
            xi, xcur, xb, shift);
        k_gemm<128, 2, 8><<<6272, 256, 0, stream>>>(
            xb, wm1b, mb1 + i * 512, nullptr, hid, 512, 0);
        k_gemm_ln<512><<<1568, 256, 0, stream>>>(
            hid, wm2b, mb2 + i * 128, n2g + i * 128, n2b + i * 128,
            xcur, xcur, xb, 0);
    }
    k_cvtw<<<64, 256, 0, stream>>>(pmw, wpmb, 64, 256);
    k_pmln<<<6272, 256, 0, stream>>>(xcur, pmg, pmb, pmin);
    k_gemm<512, 0, 4><<<784, 256, 0, stream>>>(
        pmin, wpmb, nullptr, nullptr, out, 256, 0);
}